// Round 6
// baseline (386.416 us; speedup 1.0000x reference)
//
#include <hip/hip_runtime.h>
#include <hip/hip_fp16.h>

// SSIM loss, fused: (32,3,512,512) fp32, 11x11 avg pools, out = 1 - mean(ssim_map).
//
// R6: occupancy push on the R3/R5 structure.
//  H = (Sum p, Sum t, Sum p^2+t^2, Sum pt) per cell, packed 2x half2 (8 B).
//  (components <= 242, fp16 err ~7e-4 relative -> final mean err << 2e-2 threshold)
//  Tile 64x22, NROWS=32 halo rows -> LDS 16.4 KB; launch_bounds(256,6)
//  -> 6 blocks/CU (24 waves/CU) vs R5's 3 (12).
//  Stage B: thread = (halo row j of 32, 8-col run rn of 8) -> 256/256 active.
//    6 aligned float4 loads/tensor (48-float register window), horizontal
//    11-window slid in registers, 8 swizzled 8B LDS writes.
//  Stage C: lane = x, XOR-swizzled b64 reads (uniform banks), wave w owns
//    6/6/6/4 output rows, 10-row running sum in registers.
//  Block reduce -> atomicAdd(double); finalize: out = 1 - sum/N.

#define IMGW 512
#define IMGPIX (IMGW * IMGW)
#define TW 64
#define TH 22
#define NROWS 32          // TH + 10 halo
#define SH 64             // LDS row stride in cells
#define NTILY 24          // ceil(512/22) -> last band clipped
#define NIMG 96

__global__ __launch_bounds__(256, 6)
void ssim_partial(const float* __restrict__ pred,
                  const float* __restrict__ target,
                  double* __restrict__ accum)
{
    __shared__ uint2 sH[NROWS * SH];   // 16384 B
    __shared__ float wpart[4];

    const int tid = threadIdx.x;
    const int bx = blockIdx.x, by = blockIdx.y, img = blockIdx.z;
    const float* __restrict__ p = pred   + (size_t)img * IMGPIX;
    const float* __restrict__ t = target + (size_t)img * IMGPIX;
    const int gy0 = by * TH;

    // ---- Stage B: horizontal 11-sums of 4 planes, sliding in registers ----
    {
        const int j  = tid >> 3;          // halo row 0..31
        const int rn = tid & 7;           // 8-col run
        const int rv = gy0 - 5 + j;       // image row (OOB -> zero row)
        const bool rowok = (unsigned)rv < (unsigned)IMGW;
        const int xbase = bx * TW + rn * 8;

        float fp[24], ft[24];
#pragma unroll
        for (int c = 0; c < 6; ++c) {
            const int gx = xbase - 8 + 4 * c;     // multiple of 4 -> aligned float4
            float4 pv = {0.f, 0.f, 0.f, 0.f};
            float4 tv = {0.f, 0.f, 0.f, 0.f};
            if (rowok && (unsigned)gx < (unsigned)IMGW) {
                const size_t off = (size_t)rv * IMGW + gx;
                pv = *(const float4*)(p + off);
                tv = *(const float4*)(t + off);
            }
            fp[4*c+0] = pv.x; fp[4*c+1] = pv.y; fp[4*c+2] = pv.z; fp[4*c+3] = pv.w;
            ft[4*c+0] = tv.x; ft[4*c+1] = tv.y; ft[4*c+2] = tv.z; ft[4*c+3] = tv.w;
        }
        // output x = xbase+k has window indices i = k+3 .. k+13 (x = xbase-8+i)
        float s1 = 0.f, s2 = 0.f, s3 = 0.f, s4 = 0.f;
#pragma unroll
        for (int i = 3; i <= 13; ++i) {
            s1 += fp[i];
            s2 += ft[i];
            s3 += fp[i] * fp[i] + ft[i] * ft[i];
            s4 += fp[i] * ft[i];
        }
        const int jb   = j * SH;
        const int cxor = j & 7;
        const int cb   = rn * 8;
#pragma unroll
        for (int k = 0; k < 8; ++k) {
            if (k > 0) {
                const int a = k + 13, b = k + 2;
                s1 += fp[a] - fp[b];
                s2 += ft[a] - ft[b];
                s3 += (fp[a] * fp[a] + ft[a] * ft[a])
                    - (fp[b] * fp[b] + ft[b] * ft[b]);
                s4 += fp[a] * ft[a] - fp[b] * ft[b];
            }
            const __half2 ha = __float22half2_rn(make_float2(s1, s2));
            const __half2 hb = __float22half2_rn(make_float2(s3, s4));
            uint2 cell;
            cell.x = *(const unsigned int*)&ha;
            cell.y = *(const unsigned int*)&hb;
            sH[jb + ((cb + k) ^ cxor)] = cell;
        }
    }
    __syncthreads();

    // ---- Stage C: vertical 11-sums (lane = x, swizzled b64 reads), SSIM ----
    const float inv = 1.0f / 121.0f;
    const float C1 = 1e-4f, C2 = 9e-4f;
    const int lane = tid & 63;
    const int w    = tid >> 6;
    const int r0   = w * 6;                    // waves 0..2: 6 rows, wave 3: 4 rows
    const int nrw  = (w < 3) ? 6 : 4;

    float4 r[6];
    float4 S = {0.f, 0.f, 0.f, 0.f};
#pragma unroll
    for (int i = 0; i < 10; ++i) {
        const int row = r0 + i;
        const uint2 cell = sH[row * SH + (lane ^ (row & 7))];
        const float2 f1 = __half22float2(*(const __half2*)&cell.x);
        const float2 f2 = __half22float2(*(const __half2*)&cell.y);
        if (i < 6) r[i] = make_float4(f1.x, f1.y, f2.x, f2.y);
        S.x += f1.x; S.y += f1.y; S.z += f2.x; S.w += f2.y;
    }
    float local = 0.f;
#pragma unroll
    for (int k = 0; k < 6; ++k) {
        if (k >= nrw) break;                   // wave-uniform
        const int row = r0 + 10 + k;
        const uint2 cell = sH[row * SH + (lane ^ (row & 7))];
        const float2 f1 = __half22float2(*(const __half2*)&cell.x);
        const float2 f2 = __half22float2(*(const __half2*)&cell.y);
        const float W1 = S.x + f1.x;           // 11-row window sums
        const float W2 = S.y + f1.y;
        const float W3 = S.z + f2.x;
        const float W4 = S.w + f2.y;
        S.x = W1 - r[k].x; S.y = W2 - r[k].y;
        S.z = W3 - r[k].z; S.w = W4 - r[k].w;

        if (gy0 + r0 + k < IMGW) {             // clip last band (by = 23)
            const float mu1 = W1 * inv, mu2 = W2 * inv;
            const float E3  = W3 * inv, E12 = W4 * inv;
            const float mu11 = mu1 * mu1, mu22 = mu2 * mu2, mu12 = mu1 * mu2;
            const float num = (2.f * mu12 + C1) * (2.f * (E12 - mu12) + C2);
            const float den = (mu11 + mu22 + C1) * ((E3 - mu11 - mu22) + C2);
            local += num / den;
        }
    }

    // ---- block reduce -> one double atomic per block ----
#pragma unroll
    for (int off = 32; off > 0; off >>= 1)
        local += __shfl_down(local, off, 64);
    if ((tid & 63) == 0) wpart[tid >> 6] = local;
    __syncthreads();
    if (tid == 0)
        atomicAdd(accum, (double)(wpart[0] + wpart[1] + wpart[2] + wpart[3]));
}

__global__ void ssim_finalize(const double* __restrict__ accum,
                              float* __restrict__ out) {
    const double n = 25165824.0;  // 32*3*512*512
    out[0] = (float)(1.0 - accum[0] / n);
}

extern "C" void kernel_launch(void* const* d_in, const int* in_sizes, int n_in,
                              void* d_out, int out_size, void* d_ws, size_t ws_size,
                              hipStream_t stream) {
    const float* pred   = (const float*)d_in[0];
    const float* target = (const float*)d_in[1];
    float* out = (float*)d_out;
    double* accum = (double*)d_ws;

    hipMemsetAsync(d_ws, 0, sizeof(double), stream);

    dim3 grid(IMGW / TW, NTILY, NIMG);  // 8 x 24 x 96
    dim3 block(256);
    ssim_partial<<<grid, block, 0, stream>>>(pred, target, accum);
    ssim_finalize<<<1, 1, 0, stream>>>(accum, out);
}